// Round 3
// baseline (115.858 us; speedup 1.0000x reference)
//
#include <hip/hip_runtime.h>
#include <hip/hip_bf16.h>

// SpecAugment: out = (x + noise*0.04) masked by per-sample freq/time zero masks.
// x, noise: [B=128, C=3, F=128, T=1000] f32. f0/f_len: [B,2], t0/t_len: [B,2] i32.
// Memory-bound. Flat grid-stride over float4 elements; row-skip for freq-masked
// rows (saves both input reads); NON-TEMPORAL stores (native clang vector type —
// HIP's float4 struct is rejected by the builtin) so the write-once output
// doesn't evict the re-read inputs from the 256 MB L3.

#define B 128
#define C 3
#define Fd 128
#define T 1000
#define NOISE_STD 0.04f

typedef float  f32x4 __attribute__((ext_vector_type(4)));
typedef int    i32x2 __attribute__((ext_vector_type(2)));

constexpr int ROWS       = B * C * Fd;        // 49152
constexpr int V4_PER_ROW = T / 4;             // 250
constexpr int NV4        = ROWS * V4_PER_ROW; // 12,288,000 float4s

__global__ __launch_bounds__(256) void specaug_kernel(
    const float* __restrict__ x, const float* __restrict__ noise,
    const int* __restrict__ f0, const int* __restrict__ f_len,
    const int* __restrict__ t0, const int* __restrict__ t_len,
    float* __restrict__ out)
{
    const int gid    = blockIdx.x * blockDim.x + threadIdx.x;
    const int stride = gridDim.x * blockDim.x;

    for (int i = gid; i < NV4; i += stride) {
        const unsigned row = (unsigned)i / (unsigned)V4_PER_ROW;   // magic-mul
        const int rem = i - (int)row * V4_PER_ROW;
        const int b   = (int)(row / (unsigned)(C * Fd));
        const int f   = (int)(row & (Fd - 1));                     // row % 128

        const i32x2 fa = reinterpret_cast<const i32x2*>(f0)[b];
        const i32x2 fl = reinterpret_cast<const i32x2*>(f_len)[b];
        const bool fmask = (f >= fa.x && f < fa.x + fl.x) ||
                           (f >= fa.y && f < fa.y + fl.y);

        f32x4* outp = reinterpret_cast<f32x4*>(out) + i;

        if (fmask) {
            // Whole row zeroed — skip both input reads.
            f32x4 z = {0.f, 0.f, 0.f, 0.f};
            __builtin_nontemporal_store(z, outp);
            continue;
        }

        const i32x2 ta = reinterpret_cast<const i32x2*>(t0)[b];
        const i32x2 tl = reinterpret_cast<const i32x2*>(t_len)[b];

        const f32x4 xv = reinterpret_cast<const f32x4*>(x)[i];
        const f32x4 nv = reinterpret_cast<const f32x4*>(noise)[i];

        const int t = rem * 4;
        f32x4 ov;
#pragma unroll
        for (int k = 0; k < 4; ++k) {
            const int tt = t + k;
            const bool tmask = (tt >= ta.x && tt < ta.x + tl.x) ||
                               (tt >= ta.y && tt < ta.y + tl.y);
            ov[k] = tmask ? 0.f : fmaf(nv[k], NOISE_STD, xv[k]);
        }
        __builtin_nontemporal_store(ov, outp);
    }
}

extern "C" void kernel_launch(void* const* d_in, const int* in_sizes, int n_in,
                              void* d_out, int out_size, void* d_ws, size_t ws_size,
                              hipStream_t stream)
{
    const float* x     = (const float*)d_in[0];
    const float* noise = (const float*)d_in[1];
    const int*   f0    = (const int*)d_in[2];
    const int*   f_len = (const int*)d_in[3];
    const int*   t0    = (const int*)d_in[4];
    const int*   t_len = (const int*)d_in[5];
    float* out = (float*)d_out;

    const int nblocks = 2048;   // grid-stride; ~23 float4 iters/thread
    specaug_kernel<<<nblocks, 256, 0, stream>>>(x, noise, f0, f_len, t0, t_len, out);
}